// Round 1
// baseline (34034.152 us; speedup 1.0000x reference)
//
#include <hip/hip_runtime.h>
#include <hip/hip_cooperative_groups.h>

namespace cg = cooperative_groups;

// Problem constants
#define N_MEL 80
#define ENC   512
#define ARNN  1024
#define PRE   256
#define ADIM  128
#define NFILT 32
#define KS    31
#define BSZ   16
#define TENC  128
#define TDEC  128

// Workspace layout (float offsets)
#define OFF_XA     0u          // [128][16][4096] precomputed x@Wih_x^T + bih + bhh
#define OFF_X      8388608u    // [128][16][256]  prenet out
#define OFF_H1     8912896u    // [128][16][256]  prenet hidden
#define OFF_DECIN  9437184u    // [128][16][80]
#define OFF_PM     9601024u    // [16][128][128]  processed memory
#define OFF_ATTNH  9863168u    // [2][16][1024]
#define OFF_ATTNC  9895936u    // [16][1024]
#define OFF_DECH   9912320u    // [2][16][1024]
#define OFF_DECC   9945088u    // [16][1024]
#define OFF_CTX    9961472u    // [2][16][512]
#define OFF_AW     9977856u    // [2][16][128]
#define OFF_AWC    9981952u    // [2][16][128]
#define STATE_FLOATS 122880    // from OFF_ATTNH to end

__device__ __forceinline__ float sigmf(float x) { return 1.0f / (1.0f + __expf(-x)); }
// tanh via exp, safe at +/-inf arguments: 1 - 2/(e^{2x}+1)
__device__ __forceinline__ float tanhfast(float x) { return 1.0f - 2.0f / (__expf(2.0f * x) + 1.0f); }

// ---------------- precompute kernels ----------------

__global__ void __launch_bounds__(1024) build_decin(const float* __restrict__ mels,
                                                    float* __restrict__ decin) {
    int idx = blockIdx.x * 1024 + threadIdx.x;  // 128*16*80 = 163840
    if (idx >= 128 * 16 * 80) return;
    int t = idx / 1280, r = idx % 1280;
    int b = r / 80, m = r % 80;
    decin[idx] = (t == 0) ? 0.f : mels[b * (80 * 128) + m * 128 + (t - 1)];
}

// C[M][N] = act(A[M][K] @ B[N][K]^T + bias1 + bias2); M,N multiples of 64.
__global__ void __launch_bounds__(256) gemm_kernel(
    const float* __restrict__ A, int lda,
    const float* __restrict__ B, int ldb,
    float* __restrict__ C, int ldc,
    int M, int N, int K,
    const float* __restrict__ bias1, const float* __restrict__ bias2, int relu) {
    __shared__ float As[16][68];
    __shared__ float Bs[16][68];
    int tid = threadIdx.x;
    int tn = tid & 15, tm = tid >> 4;
    int m0 = blockIdx.y * 64, n0 = blockIdx.x * 64;
    float acc[4][4] = {};
    for (int k0 = 0; k0 < K; k0 += 16) {
        for (int idx = tid; idx < 1024; idx += 256) {
            int mm = idx >> 4, kk = idx & 15;
            int kg = k0 + kk;
            As[kk][mm] = (kg < K) ? A[(size_t)(m0 + mm) * lda + kg] : 0.f;
            Bs[kk][mm] = (kg < K) ? B[(size_t)(n0 + mm) * ldb + kg] : 0.f;
        }
        __syncthreads();
#pragma unroll
        for (int kk = 0; kk < 16; kk++) {
            float av[4], bv[4];
#pragma unroll
            for (int i = 0; i < 4; i++) { av[i] = As[kk][tm * 4 + i]; bv[i] = Bs[kk][tn * 4 + i]; }
#pragma unroll
            for (int i = 0; i < 4; i++)
#pragma unroll
                for (int j = 0; j < 4; j++) acc[i][j] += av[i] * bv[j];
        }
        __syncthreads();
    }
    for (int i = 0; i < 4; i++) {
        int m = m0 + tm * 4 + i;
        for (int j = 0; j < 4; j++) {
            int n = n0 + tn * 4 + j;
            float v = acc[i][j];
            if (bias1) v += bias1[n];
            if (bias2) v += bias2[n];
            if (relu) v = fmaxf(v, 0.f);
            C[(size_t)m * ldc + n] = v;
        }
    }
}

// ---------------- main persistent cooperative kernel ----------------

struct DecArgs {
    const float* memory;
    const int* memlen;
    const float* arnn_wih;
    const float* arnn_whh;
    const float* drnn_wih;
    const float* drnn_whh;
    const float* drnn_bih;
    const float* drnn_bhh;
    const float* query_w;
    const float* v_w;
    const float* conv_w;
    const float* dense_w;
    const float* proj_w;
    const float* proj_b;
    const float* gate_w;
    const float* gate_b;
    float* ws;
    float* out;
};

__global__ void __launch_bounds__(1024) decoder_main(DecArgs A) {
    cg::grid_group grid = cg::this_grid();
    const int tid = threadIdx.x;
    const int wv = tid >> 6;
    const int lane = tid & 63;
    const int blk = blockIdx.x;
    float* ws = A.ws;

    __shared__ float s_stage[16 * 516];  // 33KB: input staging for LSTM GEMMs
    __shared__ float s_ah[1024];
    __shared__ float s_loc[128 * 33];
    __shared__ float s_pq[128];
    __shared__ float s_ev[128];
    __shared__ float s_aw2[128];
    __shared__ float s_awl[128];
    __shared__ float s_awcl[128];
    __shared__ float s_ep[1024];
    __shared__ float s_red[2];

    // zero-init recurrent state (ws poisoned 0xAA before every call)
    {
        int g = blk * 1024 + tid;
        if (g < STATE_FLOATS) ws[OFF_ATTNH + g] = 0.f;
    }
    grid.sync();

    // fixed wave/lane mapping for the LSTM stages
    const int jj = blk * 4 + (wv & 3);   // hidden unit [0,1024)
    const int bq = wv >> 2;              // batch quartet
    const int bl = lane >> 4, ks = lane & 15;
    const int bb = bq * 4 + bl;          // batch element [0,16)

    auto lstm_stage = [&](int isD, int t, int wpar, int rpar) {
        float acc0 = 0.f, acc1 = 0.f, acc2 = 0.f, acc3 = 0.f;
        const int nch = isD ? 5 : 3;
        for (int ch = 0; ch < nch; ch++) {
            const float* P; int S, Pcol;
            const float* W; int Wst, Wcol;
            if (!isD) {
                // attn LSTM: in = [ctx(512) | attn_h(1024)], W = [wih[:,256:768] | whh]
                if (ch == 0) { P = ws + OFF_CTX + rpar * 8192; S = 512; Pcol = 0;
                               W = A.arnn_wih; Wst = 768; Wcol = 256; }
                else { P = ws + OFF_ATTNH + rpar * 16384; S = 1024; Pcol = (ch - 1) * 512;
                       W = A.arnn_whh; Wst = 1024; Wcol = (ch - 1) * 512; }
            } else {
                // dec LSTM: in = [attn_h(1024) | ctx2(512) | dec_h(1024)], W = [drnn_wih | drnn_whh]
                if (ch < 2) { P = ws + OFF_ATTNH + wpar * 16384; S = 1024; Pcol = ch * 512;
                              W = A.drnn_wih; Wst = 1536; Wcol = ch * 512; }
                else if (ch == 2) { P = ws + OFF_CTX + wpar * 8192; S = 512; Pcol = 0;
                                    W = A.drnn_wih; Wst = 1536; Wcol = 1024; }
                else { P = ws + OFF_DECH + rpar * 16384; S = 1024; Pcol = (ch - 3) * 512;
                       W = A.drnn_whh; Wst = 1024; Wcol = (ch - 3) * 512; }
            }
            __syncthreads();
            for (int idx = tid; idx < 8192; idx += 1024) {
                int b2 = idx >> 9, kl = idx & 511;
                s_stage[b2 * 516 + kl] = P[b2 * S + Pcol + kl];
            }
            __syncthreads();
            const float* wp0 = W + jj * Wst + Wcol;
#pragma unroll
            for (int i = 0; i < 8; i++) {
                int kl = ks * 4 + i * 64;
                float4 iv = *reinterpret_cast<const float4*>(&s_stage[bb * 516 + kl]);
                float4 w0 = *reinterpret_cast<const float4*>(wp0 + kl);
                float4 w1 = *reinterpret_cast<const float4*>(wp0 + 1024 * Wst + kl);
                float4 w2 = *reinterpret_cast<const float4*>(wp0 + 2048 * Wst + kl);
                float4 w3 = *reinterpret_cast<const float4*>(wp0 + 3072 * Wst + kl);
                acc0 += iv.x * w0.x + iv.y * w0.y + iv.z * w0.z + iv.w * w0.w;
                acc1 += iv.x * w1.x + iv.y * w1.y + iv.z * w1.z + iv.w * w1.w;
                acc2 += iv.x * w2.x + iv.y * w2.y + iv.z * w2.z + iv.w * w2.w;
                ac3:;
                acc3 += iv.x * w3.x + iv.y * w3.y + iv.z * w3.z + iv.w * w3.w;
            }
        }
#pragma unroll
        for (int off = 1; off < 16; off <<= 1) {
            acc0 += __shfl_xor(acc0, off);
            acc1 += __shfl_xor(acc1, off);
            acc2 += __shfl_xor(acc2, off);
            acc3 += __shfl_xor(acc3, off);
        }
        if (ks == 0) {
            float G0, G1, G2, G3;
            float* Cst; float* Hst;
            if (!isD) {
                const float* xa = ws + OFF_XA + (size_t)(t * 16 + bb) * 4096;
                G0 = acc0 + xa[jj];        G1 = acc1 + xa[1024 + jj];
                G2 = acc2 + xa[2048 + jj]; G3 = acc3 + xa[3072 + jj];
                Cst = ws + OFF_ATTNC; Hst = ws + OFF_ATTNH + wpar * 16384;
            } else {
                G0 = acc0 + A.drnn_bih[jj] + A.drnn_bhh[jj];
                G1 = acc1 + A.drnn_bih[1024 + jj] + A.drnn_bhh[1024 + jj];
                G2 = acc2 + A.drnn_bih[2048 + jj] + A.drnn_bhh[2048 + jj];
                G3 = acc3 + A.drnn_bih[3072 + jj] + A.drnn_bhh[3072 + jj];
                Cst = ws + OFF_DECC; Hst = ws + OFF_DECH + wpar * 16384;
            }
            float ig = sigmf(G0), fg = sigmf(G1), gg = tanhfast(G2), og = sigmf(G3);
            float c = fg * Cst[bb * 1024 + jj] + ig * gg;
            Cst[bb * 1024 + jj] = c;
            Hst[bb * 1024 + jj] = og * tanhfast(c);
        }
    };

    auto attention = [&](int t, int wpar, int rpar) {
        const int b = blk;
        s_ah[tid] = ws[OFF_ATTNH + wpar * 16384 + b * 1024 + tid];
        if (tid < 128) {
            s_awl[tid] = ws[OFF_AW + rpar * 2048 + b * 128 + tid];
            s_awcl[tid] = ws[OFF_AWC + rpar * 2048 + b * 128 + tid];
        }
        __syncthreads();
        // conv (location features) + pq (query projection)
        for (int idx = tid; idx < 4096; idx += 1024) {
            int f = idx >> 7, tt = idx & 127;
            const float* w0 = A.conv_w + f * 62;
            float s = 0.f;
#pragma unroll
            for (int k = 0; k < 31; k++) {
                int j = tt + k - 15;
                if (j >= 0 && j < 128) s += w0[k] * s_awl[j] + w0[31 + k] * s_awcl[j];
            }
            s_loc[tt * 33 + f] = s;
        }
        {
#pragma unroll
            for (int ii = 0; ii < 8; ii++) {
                int a = wv * 8 + ii;
                const float* qw = A.query_w + a * 1024;
                float s = 0.f;
#pragma unroll
                for (int q = 0; q < 4; q++) {
                    int k = q * 256 + lane * 4;
                    float4 h4 = *reinterpret_cast<const float4*>(&s_ah[k]);
                    float4 w4 = *reinterpret_cast<const float4*>(&qw[k]);
                    s += h4.x * w4.x + h4.y * w4.y + h4.z * w4.z + h4.w * w4.w;
                }
#pragma unroll
                for (int off = 1; off < 64; off <<= 1) s += __shfl_xor(s, off);
                if (lane == 0) s_pq[a] = s;
            }
        }
        __syncthreads();
        // energies
        {
            int tt = tid >> 3, sl = tid & 7;
            float part = 0.f;
            for (int i = 0; i < 16; i++) {
                int a = i * 8 + sl;
                float lp = 0.f;
                const float* dw = A.dense_w + a * 32;
#pragma unroll
                for (int f = 0; f < 32; f++) lp += s_loc[tt * 33 + f] * dw[f];
                float arg = s_pq[a] + lp + ws[OFF_PM + (b * 128 + tt) * 128 + a];
                part += A.v_w[a] * tanhfast(arg);
            }
            s_ep[tid] = part;
        }
        __syncthreads();
        int ml = A.memlen[b];
        if (tid < 128) {
            float s = 0.f;
#pragma unroll
            for (int q = 0; q < 8; q++) s += s_ep[tid * 8 + q];
            if (tid >= ml) s = -1e30f;
            s_ev[tid] = s;
        }
        __syncthreads();
        if (wv == 0) {
            float m = fmaxf(s_ev[lane], s_ev[lane + 64]);
#pragma unroll
            for (int off = 1; off < 64; off <<= 1) m = fmaxf(m, __shfl_xor(m, off));
            if (lane == 0) s_red[0] = m;
        }
        __syncthreads();
        if (tid < 128) s_aw2[tid] = __expf(s_ev[tid] - s_red[0]);
        __syncthreads();
        if (wv == 0) {
            float s = s_aw2[lane] + s_aw2[lane + 64];
#pragma unroll
            for (int off = 1; off < 64; off <<= 1) s += __shfl_xor(s, off);
            if (lane == 0) s_red[1] = 1.f / s;
        }
        __syncthreads();
        if (tid < 128) {
            float val = s_aw2[tid] * s_red[1];
            s_aw2[tid] = val;
            ws[OFF_AW + wpar * 2048 + b * 128 + tid] = val;
            ws[OFF_AWC + wpar * 2048 + b * 128 + tid] = s_awcl[tid] + val;
            A.out[165888 + b * 16384 + t * 128 + tid] = val;  // alignments
        }
        __syncthreads();
        if (tid < 512) {
            const float* mb = A.memory + (size_t)b * 65536 + tid;
            float acc = 0.f;
            for (int tt2 = 0; tt2 < 128; tt2++) acc += s_aw2[tt2] * mb[tt2 * 512];
            ws[OFF_CTX + wpar * 8192 + b * 512 + tid] = acc;
        }
    };

    auto eout = [&](int tdone) {
        int widx = (blk - 16) * 16 + wv;
        if (widx >= 1296) return;
        int ppar = tdone & 1;
        int b; const float* wrow; float bias; float* dst;
        if (widx < 1280) {
            b = widx / 80; int m = widx % 80;
            wrow = A.proj_w + m * 1536; bias = A.proj_b[m];
            dst = A.out + (size_t)(b * 80 + m) * 128 + tdone;
        } else {
            b = widx - 1280;
            wrow = A.gate_w; bias = A.gate_b[0];
            dst = A.out + 163840 + b * 128 + tdone;
        }
        const float* h1p = ws + OFF_DECH + ppar * 16384 + b * 1024;
        const float* c1p = ws + OFF_CTX + ppar * 8192 + b * 512;
        float s = 0.f;
#pragma unroll
        for (int q = 0; q < 6; q++) {
            int k = q * 256 + lane * 4;
            float4 w4 = *reinterpret_cast<const float4*>(&wrow[k]);
            float4 h4;
            if (k < 1024) h4 = *reinterpret_cast<const float4*>(&h1p[k]);
            else h4 = *reinterpret_cast<const float4*>(&c1p[k - 1024]);
            s += w4.x * h4.x + w4.y * h4.y + w4.z * h4.z + w4.w * h4.w;
        }
#pragma unroll
        for (int off = 1; off < 64; off <<= 1) s += __shfl_xor(s, off);
        if (lane == 0) *dst = s + bias;
    };

    for (int t = 0; t < 128; t++) {
        int wpar = t & 1, rpar = wpar ^ 1;
        lstm_stage(0, t, wpar, rpar);
        grid.sync();
        if (blk < 16) attention(t, wpar, rpar);
        else if (t >= 1) eout(t - 1);
        grid.sync();
        lstm_stage(1, t, wpar, rpar);
        grid.sync();
    }
    if (blk >= 16) eout(127);
}

// ---------------- launcher ----------------

extern "C" void kernel_launch(void* const* d_in, const int* in_sizes, int n_in,
                              void* d_out, int out_size, void* d_ws, size_t ws_size,
                              hipStream_t stream) {
    (void)in_sizes; (void)n_in; (void)out_size; (void)ws_size;
    const float* memory    = (const float*)d_in[0];
    const float* mels      = (const float*)d_in[1];
    const int*   memlen    = (const int*)d_in[2];
    const float* prenet_w1 = (const float*)d_in[3];
    const float* prenet_w2 = (const float*)d_in[4];
    const float* arnn_wih  = (const float*)d_in[5];
    const float* arnn_whh  = (const float*)d_in[6];
    const float* arnn_bih  = (const float*)d_in[7];
    const float* arnn_bhh  = (const float*)d_in[8];
    const float* query_w   = (const float*)d_in[9];
    const float* memory_w  = (const float*)d_in[10];
    const float* v_w       = (const float*)d_in[11];
    const float* conv_w    = (const float*)d_in[12];
    const float* dense_w   = (const float*)d_in[13];
    const float* drnn_wih  = (const float*)d_in[14];
    const float* drnn_whh  = (const float*)d_in[15];
    const float* drnn_bih  = (const float*)d_in[16];
    const float* drnn_bhh  = (const float*)d_in[17];
    const float* proj_w    = (const float*)d_in[18];
    const float* proj_b    = (const float*)d_in[19];
    const float* gate_w    = (const float*)d_in[20];
    const float* gate_b    = (const float*)d_in[21];
    float* ws = (float*)d_ws;
    float* out = (float*)d_out;

    build_decin<<<dim3(160), dim3(1024), 0, stream>>>(mels, ws + OFF_DECIN);
    // prenet layer 1: [2048,80]@[80,256]^T, relu
    gemm_kernel<<<dim3(4, 32), dim3(256), 0, stream>>>(ws + OFF_DECIN, 80, prenet_w1, 80,
                                                       ws + OFF_H1, 256, 2048, 256, 80,
                                                       nullptr, nullptr, 1);
    // prenet layer 2
    gemm_kernel<<<dim3(4, 32), dim3(256), 0, stream>>>(ws + OFF_H1, 256, prenet_w2, 256,
                                                       ws + OFF_X, 256, 2048, 256, 256,
                                                       nullptr, nullptr, 1);
    // x-part of attention-LSTM gates + both biases
    gemm_kernel<<<dim3(64, 32), dim3(256), 0, stream>>>(ws + OFF_X, 256, arnn_wih, 768,
                                                        ws + OFF_XA, 4096, 2048, 4096, 256,
                                                        arnn_bih, arnn_bhh, 0);
    // processed memory
    gemm_kernel<<<dim3(2, 32), dim3(256), 0, stream>>>(memory, 512, memory_w, 512,
                                                       ws + OFF_PM, 128, 2048, 128, 512,
                                                       nullptr, nullptr, 0);

    DecArgs a;
    a.memory = memory; a.memlen = memlen;
    a.arnn_wih = arnn_wih; a.arnn_whh = arnn_whh;
    a.drnn_wih = drnn_wih; a.drnn_whh = drnn_whh;
    a.drnn_bih = drnn_bih; a.drnn_bhh = drnn_bhh;
    a.query_w = query_w; a.v_w = v_w;
    a.conv_w = conv_w; a.dense_w = dense_w;
    a.proj_w = proj_w; a.proj_b = proj_b;
    a.gate_w = gate_w; a.gate_b = gate_b;
    a.ws = ws; a.out = out;
    void* kargs[] = { &a };
    hipLaunchCooperativeKernel((const void*)decoder_main, dim3(256), dim3(1024),
                               kargs, 0, stream);
}